// Round 6
// baseline (565.751 us; speedup 1.0000x reference)
//
#include <hip/hip_runtime.h>
#include <hip/hip_fp16.h>

typedef __attribute__((ext_vector_type(4))) float f32x4;
typedef __attribute__((ext_vector_type(8))) _Float16 f16x8;
typedef __attribute__((ext_vector_type(4))) _Float16 f16x4;

// ---------------- helpers ----------------
__device__ __forceinline__ void gload_lds16(const void* gp, void* lp) {
    __builtin_amdgcn_global_load_lds(
        (const __attribute__((address_space(1))) void*)gp,
        (__attribute__((address_space(3))) void*)lp, 16, 0, 0);
}

// ---------------- RoPE tables: cos/sin (2048 x 512) f32 ----------------
__global__ void rope_tables_k(float* __restrict__ cosT, float* __restrict__ sinT) {
    int idx = blockIdx.x * 256 + threadIdx.x;   // 2048*512 total
    int s = idx >> 9, j = idx & 511;
    float invf = exp2f(-13.287712379549449f * (float)j * (1.0f / 512.0f)); // 10000^(-j/512)
    float ang = (float)s * invf;
    float sn, cs;
    sincosf(ang, &sn, &cs);
    cosT[idx] = cs;
    sinT[idx] = sn;
}

// ---------------- f32 -> f16 straight convert ----------------
__global__ void f32_to_f16_vec(const float* __restrict__ in, _Float16* __restrict__ out) {
    long i = ((long)blockIdx.x * 256 + threadIdx.x) * 4;
    f32x4 v = *(const f32x4*)(in + i);
    f16x4 h;
#pragma unroll
    for (int e = 0; e < 4; ++e) h[e] = (_Float16)v[e];
    *(f16x4*)(out + i) = h;
}

// ---------------- transpose + convert: in (R x C) f32 -> out (C x R) f16 ----------------
__global__ void transpose_f32_to_f16(const float* __restrict__ in, _Float16* __restrict__ out,
                                     int R, int C) {
    __shared__ _Float16 tile[32][36];
    const int c0 = blockIdx.x * 32, r0 = blockIdx.y * 32;
    const int t = threadIdx.x;
    const int r = t >> 3, c4 = (t & 7) * 4;
    f32x4 v = *(const f32x4*)(in + (long)(r0 + r) * C + c0 + c4);
    f16x4 h;
#pragma unroll
    for (int e = 0; e < 4; ++e) h[e] = (_Float16)v[e];
    *(f16x4*)&tile[r][c4] = h;
    __syncthreads();
    const int oc = t >> 3, o4 = (t & 7) * 4;
    f16x4 o;
#pragma unroll
    for (int e = 0; e < 4; ++e) o[e] = tile[o4 + e][oc];
    *(f16x4*)(out + (long)(c0 + oc) * R + r0 + o4) = o;
}

// ---------------- RoPE in-place on qkv rows (head-mixing: pair j with j+1024) ----------------
__global__ void rope_inplace(_Float16* __restrict__ qkv, const float* __restrict__ cosT,
                             const float* __restrict__ sinT) {
    const int row = blockIdx.x;            // b*2048 + s
    const int s = row & 2047;
    const int j0 = threadIdx.x * 4;        // [0,1024)
    _Float16* base = qkv + (long)row * 6144;
    f16x4 q0 = *(const f16x4*)(base + j0);
    f16x4 q1 = *(const f16x4*)(base + 1024 + j0);
    f16x4 k0 = *(const f16x4*)(base + 2048 + j0);
    f16x4 k1 = *(const f16x4*)(base + 3072 + j0);
    const int jj = j0 & 511;
    f32x4 cs = *(const f32x4*)(cosT + (long)s * 512 + jj);
    f32x4 sn = *(const f32x4*)(sinT + (long)s * 512 + jj);
    f16x4 oq0, oq1, ok0, ok1;
#pragma unroll
    for (int e = 0; e < 4; ++e) {
        float a = (float)q0[e], b = (float)q1[e];
        oq0[e] = (_Float16)(a * cs[e] - b * sn[e]);
        oq1[e] = (_Float16)(b * cs[e] + a * sn[e]);
        float c = (float)k0[e], d = (float)k1[e];
        ok0[e] = (_Float16)(c * cs[e] - d * sn[e]);
        ok1[e] = (_Float16)(d * cs[e] + c * sn[e]);
    }
    *(f16x4*)(base + j0) = oq0;
    *(f16x4*)(base + 1024 + j0) = oq1;
    *(f16x4*)(base + 2048 + j0) = ok0;
    *(f16x4*)(base + 3072 + j0) = ok1;
}

// ---------------- V transpose: qkv v-part (b,s,h,d) -> vT (b,h,d,s) f16 ----------------
__global__ void v_transpose(const _Float16* __restrict__ qkv, _Float16* __restrict__ vT) {
    __shared__ _Float16 tile[32][36];
    const int z = blockIdx.z, b = z >> 1, h = z & 1;
    const int s0 = blockIdx.x * 32, d0 = blockIdx.y * 32;
    const int t = threadIdx.x;
    const int r = t >> 3, c4 = (t & 7) * 4;
    const _Float16* src = qkv + (long)(b * 2048 + s0 + r) * 6144 + 4096 + h * 1024 + d0 + c4;
    *(f16x4*)&tile[r][c4] = *(const f16x4*)src;
    __syncthreads();
    const int dr = t >> 3, sc = (t & 7) * 4;
    f16x4 o;
#pragma unroll
    for (int e = 0; e < 4; ++e) o[e] = tile[sc + e][dr];
    *(f16x4*)(vT + ((long)z * 1024 + d0 + dr) * 2048 + s0 + sc) = o;
}

// ---------------- softmax on f32 rows (2048), writes f16 P in place (row stride 4096 f16) ----------------
__global__ __launch_bounds__(256) void softmax_rows_f32(float* __restrict__ S, float scale) {
    const int wid = threadIdx.x >> 6, lane = threadIdx.x & 63;
    const long row = (long)blockIdx.x * 4 + wid;
    float* rp = S + row * 2048;
    f32x4 v[8];
    float mx = -1e30f;
#pragma unroll
    for (int i = 0; i < 8; ++i) {
        v[i] = *(const f32x4*)(rp + (i * 64 + lane) * 4);
#pragma unroll
        for (int e = 0; e < 4; ++e) mx = fmaxf(mx, v[i][e]);
    }
#pragma unroll
    for (int o = 32; o > 0; o >>= 1) mx = fmaxf(mx, __shfl_xor(mx, o, 64));
    float sum = 0.f;
#pragma unroll
    for (int i = 0; i < 8; ++i)
#pragma unroll
        for (int e = 0; e < 4; ++e) {
            float p = __expf(scale * (v[i][e] - mx));
            v[i][e] = p; sum += p;
        }
#pragma unroll
    for (int o = 32; o > 0; o >>= 1) sum += __shfl_xor(sum, o, 64);
    float inv = 1.0f / sum;
    _Float16* wp = (_Float16*)S + row * 4096;
#pragma unroll
    for (int i = 0; i < 8; ++i) {
        f16x4 h;
#pragma unroll
        for (int e = 0; e < 4; ++e) h[e] = (_Float16)(v[i][e] * inv);
        *(f16x4*)(wp + (i * 64 + lane) * 4) = h;
    }
}

// ---------------- softmax on f16 rows (2048), in place (row stride 2048 f16) ----------------
__global__ __launch_bounds__(256) void softmax_rows_f16(_Float16* __restrict__ S, float scale) {
    const int wid = threadIdx.x >> 6, lane = threadIdx.x & 63;
    const long row = (long)blockIdx.x * 4 + wid;
    _Float16* rp = S + row * 2048;
    f16x8 v[4];
    float f[32];
    float mx = -1e30f;
#pragma unroll
    for (int i = 0; i < 4; ++i) {
        v[i] = *(const f16x8*)(rp + i * 512 + lane * 8);
#pragma unroll
        for (int e = 0; e < 8; ++e) {
            f[i * 8 + e] = (float)v[i][e];
            mx = fmaxf(mx, f[i * 8 + e]);
        }
    }
#pragma unroll
    for (int o = 32; o > 0; o >>= 1) mx = fmaxf(mx, __shfl_xor(mx, o, 64));
    float sum = 0.f;
#pragma unroll
    for (int i = 0; i < 32; ++i) {
        float p = __expf(scale * (f[i] - mx));
        f[i] = p; sum += p;
    }
#pragma unroll
    for (int o = 32; o > 0; o >>= 1) sum += __shfl_xor(sum, o, 64);
    float inv = 1.0f / sum;
#pragma unroll
    for (int i = 0; i < 4; ++i) {
        f16x8 h;
#pragma unroll
        for (int e = 0; e < 8; ++e) h[e] = (_Float16)(f[i * 8 + e] * inv);
        *(f16x8*)(rp + i * 512 + lane * 8) = h;
    }
}

// ---------------- GEMM 256x128, BK=32, 4 waves (2x2), ring-3 LDS, 2 blocks/CU ----------------
// C = A(MxK, lda) * B^T (B stored NxK row-major, ldb). K multiple of 32, NT=K/32 >= 3.
// Ring-3 slots of 24 KB (A 16 KB + B 8 KB); stage distance 2; gate = counted vmcnt(6),
// ONE barrier per K-tile (ring-3 closes the WAR window: slot (t+2)%3 was last read in
// tile t-1, and all waves' t-1 reads complete before any wave passes barrier(t)).
// LDS rows 64 B; granule(16B) swizzle g ^= (row>>1)&3 (16 lanes -> 8 banks x 2-way = free),
// applied as inverse-swizzled GLOBAL source col (global_load_lds dest must stay linear).
// 2 blocks/CU (72 KB LDS, ~240 regs/wave) -> the other block's MFMAs fill this block's
// gate/read stalls (the round-3..5 single-block designs were CU-lockstep at 43-45%).
template <bool OUT_F16, bool BIAS>
__global__ __launch_bounds__(256, 2)
void gemm_rg(const _Float16* __restrict__ A, const _Float16* __restrict__ B,
             void* __restrict__ Cv, const float* __restrict__ bias,
             int K, int lda, int ldb, int ldc, int zmod,
             long a1, long a2, long b1, long b2, long c1, long c2) {
    __shared__ char lds[73728];   // 3 x (A 16384 + B 8192)
    const int z = blockIdx.z, zq = z / zmod, zr = z - zq * zmod;
    A += zq * a1 + zr * a2;
    B += zq * b1 + zr * b2;
    const long coff = zq * c1 + zr * c2;
    const int tm = blockIdx.y * 256, tn = blockIdx.x * 128;
    const int t = threadIdx.x;               // 256
    const int lane = t & 63, wid = t >> 6;   // 4 waves
    const int wr = wid >> 1, wc = wid & 1;   // wave tile: rows wr*128, cols wc*64
    const int fr = lane & 15, kg = lane >> 4;

    // staging source (inverse-swizzled global granule): thread t covers LDS row t>>2, pos t&3
    const int strow = t >> 2;                          // 0..63 per instr
    const int stcol = 8 * ((t & 3) ^ ((t >> 3) & 3));  // granule G = pos ^ ((row>>1)&3)
    const _Float16* gA = A + (long)(tm + strow) * lda + stcol;
    const _Float16* gB = B + (long)(tn + strow) * ldb + stcol;
    const int ldsw = wid * 1024;             // wave-uniform chunk within each 4KB instr block

    // ds_read swizzle: row = *+fr with frag row base ≡ 0 mod 16 -> (row>>1)&3 = (fr>>1)&3
    const int swz = 16 * (kg ^ ((fr >> 1) & 3));
    const int arow = (wr * 128 + fr) * 64 + swz;           // + slot, + m*1024
    const int brow = 16384 + (wc * 64 + fr) * 64 + swz;    // + slot, + n*1024

    const int NT = K >> 5;
    f32x4 acc[8][4] = {};

    auto stage = [&](int tt, int slot) {
        const long ko = (long)tt * 32;
        char* d = lds + slot * 24576 + ldsw;
#pragma unroll
        for (int i = 0; i < 4; ++i)
            gload_lds16(gA + ko + (long)(i * 64) * lda, d + i * 4096);
#pragma unroll
        for (int i = 0; i < 2; ++i)
            gload_lds16(gB + ko + (long)(i * 64) * ldb, d + 16384 + i * 4096);
    };

    // prologue: stage tiles 0,1 into slots 0,1
    stage(0, 0);
    stage(1, 1);

    int st = 0, sp = 2;   // current slot, stage-target slot (= (t+2)%3)
    for (int tt = 0; tt < NT; ++tt) {
        if (tt + 1 < NT) asm volatile("s_waitcnt vmcnt(6)" ::: "memory");
        else             asm volatile("s_waitcnt vmcnt(0)" ::: "memory");
        __builtin_amdgcn_s_barrier();
        const char* buf = lds + st * 24576;
        f16x8 af[8], bf[4];
#pragma unroll
        for (int m = 0; m < 8; ++m) af[m] = *(const f16x8*)(buf + arow + m * 1024);
#pragma unroll
        for (int n = 0; n < 4; ++n) bf[n] = *(const f16x8*)(buf + brow + n * 1024);
        if (tt + 2 < NT) stage(tt + 2, sp);
        __builtin_amdgcn_s_setprio(1);
#pragma unroll
        for (int m = 0; m < 8; ++m)
#pragma unroll
            for (int n = 0; n < 4; ++n)
                acc[m][n] = __builtin_amdgcn_mfma_f32_16x16x32_f16(af[m], bf[n], acc[m][n], 0, 0, 0);
        __builtin_amdgcn_s_setprio(0);
        st = (st == 2) ? 0 : st + 1;
        sp = (sp == 2) ? 0 : sp + 1;
    }

    // epilogue: C/D layout col = lane&15, row = (lane>>4)*4 + r
    const int rb = tm + wr * 128 + (lane >> 4) * 4;
    const int cb = tn + wc * 64 + fr;
#pragma unroll
    for (int m = 0; m < 8; ++m) {
#pragma unroll
        for (int n = 0; n < 4; ++n) {
#pragma unroll
            for (int r = 0; r < 4; ++r) {
                float v = acc[m][n][r];
                const int row = rb + m * 16 + r;
                const int col = cb + n * 16;
                if (BIAS) v += bias[col];
                if (OUT_F16)
                    ((_Float16*)Cv)[coff + (long)row * ldc + col] = (_Float16)v;
                else
                    ((float*)Cv)[coff + (long)row * ldc + col] = v;
            }
        }
    }
}

extern "C" void kernel_launch(void* const* d_in, const int* in_sizes, int n_in,
                              void* d_out, int out_size, void* d_ws, size_t ws_size,
                              hipStream_t stream) {
    const float* x    = (const float*)d_in[0];   // (4,2048,2048)
    const float* wqkv = (const float*)d_in[1];   // (2048,6144)
    const float* wout = (const float*)d_in[2];   // (2048,2048)
    const float* bout = (const float*)d_in[3];   // (2048,)
    char* ws = (char*)d_ws;

    _Float16* qkv_h = (_Float16*)(ws);
    _Float16* x_h   = (_Float16*)(ws + 100663296);
    _Float16* wqkvT = (_Float16*)(ws + 134217728);
    _Float16* vT    = (_Float16*)(ws + 100663296);
    float*    cosT  = (float*)(ws + 100663296);   // alias: lives between QKV GEMM and v_transpose
    float*    sinT  = (float*)(ws + 104857600);
    _Float16* woutT = (_Float16*)(ws);
    const bool batched = ws_size >= 234881024ULL;

    // 1. x -> f16
    f32_to_f16_vec<<<dim3(16384), dim3(256), 0, stream>>>(x, x_h);
    // 2. wqkv (2048x6144) -> wqkvT (6144x2048) f16
    transpose_f32_to_f16<<<dim3(192, 64), dim3(256), 0, stream>>>(wqkv, wqkvT, 2048, 6144);
    // 3. qkv = x @ wqkv  (M=8192,N=6144,K=2048) -> f16
    gemm_rg<true, false><<<dim3(48, 32, 1), dim3(256), 0, stream>>>(
        x_h, wqkvT, (void*)qkv_h, nullptr, 2048, 2048, 2048, 6144,
        1, 0L, 0L, 0L, 0L, 0L, 0L);
    // 4. RoPE tables (x_h now dead; tables alias that region)
    rope_tables_k<<<dim3(4096), dim3(256), 0, stream>>>(cosT, sinT);
    // 5. RoPE in place on q,k halves (head-mixing rotation)
    rope_inplace<<<dim3(8192), dim3(256), 0, stream>>>(qkv_h, cosT, sinT);
    // 6. V transpose -> vT (b,h,d,s)  (overwrites table region; tables dead)
    v_transpose<<<dim3(64, 32, 8), dim3(256), 0, stream>>>(qkv_h, vT);

    if (batched) {
        _Float16* S16  = (_Float16*)(ws + 134217728);
        _Float16* aout = (_Float16*)(ws + 201326592);
        // 7. S = Q@K^T all 8 (b,h): M=N=2048,K=1024 -> f16
        gemm_rg<true, false><<<dim3(16, 8, 8), dim3(256), 0, stream>>>(
            qkv_h, qkv_h + 2048, (void*)S16, nullptr, 1024, 6144, 6144, 2048,
            2, 12582912L, 1024L, 12582912L, 1024L, 8388608L, 4194304L);
        // 8. softmax rows in place
        softmax_rows_f16<<<dim3(4096), dim3(256), 0, stream>>>(S16, 0.03125f);
        // 9. O = P@V: M=2048,N=1024,K=2048 -> aout (b,s,h*d)
        gemm_rg<true, false><<<dim3(8, 8, 8), dim3(256), 0, stream>>>(
            S16, vT, (void*)aout, nullptr, 2048, 2048, 2048, 2048,
            2, 8388608L, 4194304L, 4194304L, 2097152L, 4194304L, 1024L);
        // 10. wout -> woutT; out = aout @ wout + bout
        transpose_f32_to_f16<<<dim3(64, 64), dim3(256), 0, stream>>>(wout, woutT, 2048, 2048);
        gemm_rg<false, true><<<dim3(16, 32, 1), dim3(256), 0, stream>>>(
            aout, woutT, d_out, bout, 2048, 2048, 2048, 2048,
            1, 0L, 0L, 0L, 0L, 0L, 0L);
    } else {
        float*    S32  = (float*)(ws + 134217728);
        _Float16* aout = (_Float16*)(ws + 150994944);
        for (int z = 0; z < 8; ++z) {
            const _Float16* Az = qkv_h + (long)(z >> 1) * 12582912 + (z & 1) * 1024;
            gemm_rg<false, false><<<dim3(16, 8, 1), dim3(256), 0, stream>>>(
                Az, Az + 2048, (void*)S32, nullptr, 1024, 6144, 6144, 2048,
                1, 0L, 0L, 0L, 0L, 0L, 0L);
            softmax_rows_f32<<<dim3(512), dim3(256), 0, stream>>>(S32, 0.03125f);
            gemm_rg<true, false><<<dim3(8, 8, 1), dim3(256), 0, stream>>>(
                (const _Float16*)S32, vT + (long)z * 2097152,
                (void*)(aout + (long)(z >> 1) * 4194304 + (z & 1) * 1024), nullptr,
                2048, 4096, 2048, 2048, 1, 0L, 0L, 0L, 0L, 0L, 0L);
        }
        transpose_f32_to_f16<<<dim3(64, 64), dim3(256), 0, stream>>>(wout, woutT, 2048, 2048);
        gemm_rg<false, true><<<dim3(16, 32, 1), dim3(256), 0, stream>>>(
            aout, woutT, d_out, bout, 2048, 2048, 2048, 2048,
            1, 0L, 0L, 0L, 0L, 0L, 0L);
    }
}